// Round 7
// baseline (839.257 us; speedup 1.0000x reference)
//
#include <hip/hip_runtime.h>
#include <cstdint>
#include <cstddef>

typedef _Float16 f16x8 __attribute__((ext_vector_type(8)));
typedef _Float16 f16x4 __attribute__((ext_vector_type(4)));
typedef _Float16 f16x2 __attribute__((ext_vector_type(2)));
typedef float    f32x4 __attribute__((ext_vector_type(4)));
typedef uint32_t u32x4 __attribute__((ext_vector_type(4)));

__device__ __forceinline__ void async16(const void* g, void* l) {
  __builtin_amdgcn_global_load_lds(
      (const __attribute__((address_space(1))) void*)g,
      (__attribute__((address_space(3))) void*)l, 16, 0, 0);
}

// ---------------- fused fp32 -> fp16 convert, 5 segments in one launch ----------------
__global__ void cvt5_kernel(const float* __restrict__ s0, const float* __restrict__ s1,
                            const float* __restrict__ s2, const float* __restrict__ s3,
                            const float* __restrict__ s4,
                            _Float16* __restrict__ d0, _Float16* __restrict__ d1,
                            _Float16* __restrict__ d2, _Float16* __restrict__ d3,
                            _Float16* __restrict__ d4,
                            int n0, int n1, int n2, int n3, int n4c) {
  const float* src; _Float16* dst; int n4;
  switch (blockIdx.y) {
    case 0:  src = s0; dst = d0; n4 = n0;  break;
    case 1:  src = s1; dst = d1; n4 = n1;  break;
    case 2:  src = s2; dst = d2; n4 = n2;  break;
    case 3:  src = s3; dst = d3; n4 = n3;  break;
    default: src = s4; dst = d4; n4 = n4c; break;
  }
  int i = blockIdx.x * blockDim.x + threadIdx.x;
  int stride = gridDim.x * blockDim.x;
  for (; i < n4; i += stride) {
    float4 f = ((const float4*)src)[i];
    f16x4 o;
    o[0] = (_Float16)f.x; o[1] = (_Float16)f.y;
    o[2] = (_Float16)f.z; o[3] = (_Float16)f.w;
    ((f16x4*)dst)[i] = o;
  }
}

// ---------------- NT GEMM: C = A(M,K) * B(N,K)^T ----------------
// OUT_MODE 2: f32 C row-major (ld=N).  MINW: __launch_bounds__ min waves/EU —
//   O-proj uses 4 (forces VGPR<=128 -> 4 blocks/CU -> 1024-block grid = exactly
//   one generation, killing the 1.33-gen tail); QKV stays 3 (1536 = 2 exact gens).
// OUT_MODE 4: fused QKV epilogue WITH RoPE on Q and K:
//   cols [0,4096) -> roped f16 XQ (ld=4096); [4096,5120) -> roped f16 XK (ld=1024);
//   [5120,6144) -> f16 VT transposed (ld=M), no rope.
//   RoPE on acc in-register: pair (even d, odd d) sits in lanes (l15, l15^1);
//   fi=(col&127)>>1, s=row&sMask; even: self*cs - other*sn; odd: other*sn + self*cs.
template<int OUT_MODE, int MINW>
__global__ __launch_bounds__(256, MINW)
void gemm_nt(const _Float16* __restrict__ A, const _Float16* __restrict__ B,
             void* __restrict__ Cp, void* __restrict__ Cp2, void* __restrict__ Cp3,
             const int* __restrict__ sp,
             int M, int N, int K, int sMask) {
  __shared__ __align__(16) _Float16 As[128 * 64];
  __shared__ __align__(16) _Float16 Bs[128 * 64];
  const int tid  = threadIdx.x;
  const int wave = tid >> 6, lane = tid & 63;
  const int l15  = lane & 15, quad = lane >> 4;
  const int m0 = blockIdx.y * 128, n0 = blockIdx.x * 128;
  const int wm = (wave >> 1) * 64, wn = (wave & 1) * 64;
  f32x4 acc[4][4] = {};
  const int cbase = wave * 256;

  for (int kb = 0; kb < K; kb += 64) {
    // stage A,B tiles (128x64 f16 each) via global_load_lds, XOR chunk swizzle
    #pragma unroll
    for (int i = 0; i < 4; ++i) {
      int base = cbase + i * 64;
      int idx  = base + lane;          // chunk 0..1023
      int row  = idx >> 3, pos = idx & 7;
      int c    = pos ^ (row & 7);
      async16(A + (size_t)(m0 + row) * K + kb + c * 8, (char*)As + base * 16);
      async16(B + (size_t)(n0 + row) * K + kb + c * 8, (char*)Bs + base * 16);
    }
    __syncthreads();
    #pragma unroll
    for (int ks = 0; ks < 2; ++ks) {
      f16x8 af[4], bfv[4];
      #pragma unroll
      for (int t = 0; t < 4; ++t) {
        int ra = wm + t * 16 + l15;
        int pa = (ks * 4 + quad) ^ (ra & 7);
        af[t] = *(const f16x8*)((const char*)As + ra * 128 + pa * 16);
        int rb = wn + t * 16 + l15;
        int pb = (ks * 4 + quad) ^ (rb & 7);
        bfv[t] = *(const f16x8*)((const char*)Bs + rb * 128 + pb * 16);
      }
      #pragma unroll
      for (int mt = 0; mt < 4; ++mt)
        #pragma unroll
        for (int nt = 0; nt < 4; ++nt)
          acc[mt][nt] = __builtin_amdgcn_mfma_f32_16x16x32_f16(af[mt], bfv[nt], acc[mt][nt], 0, 0, 0);
    }
    __syncthreads();
  }

  if constexpr (OUT_MODE == 2) {
    float* Cf = (float*)Cp;
    #pragma unroll
    for (int mt = 0; mt < 4; ++mt)
      #pragma unroll
      for (int r = 0; r < 4; ++r) {
        size_t row = (size_t)(m0 + wm + mt * 16 + quad * 4 + r);
        #pragma unroll
        for (int nt = 0; nt < 4; ++nt)
          Cf[row * N + n0 + wn + nt * 16 + l15] = acc[mt][nt][r];
      }
  } else if constexpr (OUT_MODE == 4) {
    if (n0 < 5120) {           // Q or K projection: rope + f16 store
      const bool isQ = (n0 < 4096);
      _Float16* Cb = isQ ? (_Float16*)Cp : (_Float16*)Cp2;
      const int ld   = isQ ? 4096 : 1024;
      const int cof  = isQ ? 0 : 4096;
      const int start = *sp;
      const bool odd = (l15 & 1) != 0;
      #pragma unroll
      for (int mt = 0; mt < 4; ++mt)
        #pragma unroll
        for (int r = 0; r < 4; ++r) {
          int row = m0 + wm + mt * 16 + quad * 4 + r;
          float pos = (float)(start + (row & sMask));
          #pragma unroll
          for (int nt = 0; nt < 4; ++nt) {
            int col = n0 - cof + wn + nt * 16 + l15;
            int fi  = (col & 127) >> 1;
            float ang = pos * exp2f(-0.20762050593046014f * (float)fi);
            float sn, cs;
            __sincosf(ang, &sn, &cs);
            float self  = acc[mt][nt][r];
            float other = __shfl_xor(self, 1);
            float out = odd ? (other * sn + self * cs)
                            : (self * cs - other * sn);
            Cb[(size_t)row * ld + col] = (_Float16)out;
          }
        }
    } else {                   // V projection: store transposed (feature-major), no rope
      _Float16* Ct = (_Float16*)Cp3;
      #pragma unroll
      for (int mt = 0; mt < 4; ++mt)
        #pragma unroll
        for (int nt = 0; nt < 4; ++nt) {
          size_t crow = (size_t)(n0 - 5120 + wn + nt * 16 + l15);
          size_t ccol = (size_t)(m0 + wm + mt * 16 + quad * 4);
          f16x4 t;
          t[0] = (_Float16)acc[mt][nt][0]; t[1] = (_Float16)acc[mt][nt][1];
          t[2] = (_Float16)acc[mt][nt][2]; t[3] = (_Float16)acc[mt][nt][3];
          *(f16x4*)(Ct + crow * M + ccol) = t;
        }
    }
  }
}

// ---------------- flash attention, non-causal, GQA 4:1 ----------------
// R5-verified core (swapped QK^T, in-register P rebuild, 32KB LDS). R7 change:
// PV(mt) moved directly after softmax(mt) so PV(0)'s MFMAs overlap softmax(1)'s
// VALU chain (m214v36-style double-pipeline). vf re-read per mt (+16 ds_read/iter).
__global__ __launch_bounds__(256, 2)
void flash_kernel(const _Float16* __restrict__ Q, const _Float16* __restrict__ Kg,
                  const _Float16* __restrict__ Vt, _Float16* __restrict__ O,
                  int S, int T) {
  __shared__ __align__(16) _Float16 Kt[64 * 128];   // [key][d], swizzled
  __shared__ __align__(16) _Float16 Vs[128 * 64];   // [d][key], swizzled
  const int tid  = threadIdx.x;
  const int wave = tid >> 6, lane = tid & 63;
  const int l15  = lane & 15, quad = lane >> 4;
  const int qt = blockIdx.x, hq = blockIdx.y, b = blockIdx.z;
  const int kvh = hq >> 2;
  const float scale = 0.12751744f;   // log2(e)/sqrt(128): softmax in exp2 domain

  // Q fragments in registers: wave owns 32 q-rows (q = mt*16 + l15)
  f16x8 qf[2][4];
  #pragma unroll
  for (int mt = 0; mt < 2; ++mt)
    #pragma unroll
    for (int ks = 0; ks < 4; ++ks) {
      size_t row = (size_t)b * S + qt * 128 + wave * 32 + mt * 16 + l15;
      qf[mt][ks] = *(const f16x8*)(Q + row * 4096 + hq * 128 + ks * 32 + quad * 8);
    }

  const f16x8 ones = {(_Float16)1, (_Float16)1, (_Float16)1, (_Float16)1,
                      (_Float16)1, (_Float16)1, (_Float16)1, (_Float16)1};

  f32x4 oacc[2][8] = {};
  f32x4 liacc[2] = {};              // row-sums via MFMA(P, ones): q = quad*4+r
  float mi[2] = {-1e30f, -1e30f};   // running max, lane-local (q = l15)

  const int nkt = S >> 6;

  auto stageK = [&](int kt) {
    #pragma unroll
    for (int i = 0; i < 4; ++i) {
      int base = wave * 256 + i * 64;
      int idx  = base + lane;
      int row = idx >> 4, pos = idx & 15, c = pos ^ (row & 15);
      async16(Kg + (size_t)(b * S + kt * 64 + row) * 1024 + kvh * 128 + c * 8,
              (char*)Kt + base * 16);
    }
  };
  auto stageV = [&](int kt) {
    #pragma unroll
    for (int i = 0; i < 4; ++i) {
      int base = wave * 256 + i * 64;
      int idx  = base + lane;
      int row = idx >> 3, pos = idx & 7, c = pos ^ (row & 7);
      async16(Vt + (size_t)(kvh * 128 + row) * T + b * S + kt * 64 + c * 8,
              (char*)Vs + base * 16);
    }
  };

  stageK(0); stageV(0);
  __syncthreads();           // drain prologue

  // P redistribution source lanes (quad-group permute within same l15)
  const int idxA = l15 + (((quad * 2) & 3) << 4);      // elems j0..3
  const int idxB = l15 + (((quad * 2 + 1) & 3) << 4);  // elems j4..7
  const bool hiNt = (quad >> 1) != 0;                  // nt_s = 2*k2 + (quad>>1)

  for (int kt = 0; kt < nkt; ++kt) {
    // ---- S^T = K Q^T: sacc[mt][nt] holds S[key=nt*16+quad*4+r][q=mt*16+l15] ----
    f32x4 sacc[2][4] = {};
    #pragma unroll
    for (int ks = 0; ks < 4; ++ks) {
      f16x8 kf[4];
      #pragma unroll
      for (int nt = 0; nt < 4; ++nt) {
        int rk = nt * 16 + l15;
        int pp = (ks * 4 + quad) ^ (rk & 15);
        kf[nt] = *(const f16x8*)((const char*)Kt + rk * 256 + pp * 16);
      }
      __builtin_amdgcn_s_setprio(1);
      #pragma unroll
      for (int mt = 0; mt < 2; ++mt)
        #pragma unroll
        for (int nt = 0; nt < 4; ++nt)
          sacc[mt][nt] = __builtin_amdgcn_mfma_f32_16x16x32_f16(kf[nt], qf[mt][ks], sacc[mt][nt], 0, 0, 0);
      __builtin_amdgcn_s_setprio(0);
    }

    // barrier A: all waves done reading K[kt]; drains V[kt] stage (issued last iter)
    __syncthreads();
    if (kt + 1 < nkt) stageK(kt + 1);   // covered by softmax+PV, drained at barrier B

    // ---- per-mt: softmax -> in-register P rebuild -> PV (MFMA/VALU interleave) ----
    #pragma unroll
    for (int mt = 0; mt < 2; ++mt) {
      // lane-local max over 16 keys (balanced tree), then 2-step quad butterfly
      float a0 = fmaxf(fmaxf(sacc[mt][0][0], sacc[mt][0][1]), fmaxf(sacc[mt][0][2], sacc[mt][0][3]));
      float a1 = fmaxf(fmaxf(sacc[mt][1][0], sacc[mt][1][1]), fmaxf(sacc[mt][1][2], sacc[mt][1][3]));
      float a2 = fmaxf(fmaxf(sacc[mt][2][0], sacc[mt][2][1]), fmaxf(sacc[mt][2][2], sacc[mt][2][3]));
      float a3 = fmaxf(fmaxf(sacc[mt][3][0], sacc[mt][3][1]), fmaxf(sacc[mt][3][2], sacc[mt][3][3]));
      float mx = fmaxf(fmaxf(a0, a1), fmaxf(a2, a3));
      mx = fmaxf(mx, __shfl_xor(mx, 16));
      mx = fmaxf(mx, __shfl_xor(mx, 32));
      // defer-max: rescale only when running max grew materially (24 raw ~ 2^3)
      if (__any(mx > mi[mt] + 24.0f)) {
        float mnew = fmaxf(mi[mt], mx);
        float al = exp2f((mi[mt] - mnew) * scale);
        mi[mt] = mnew;
        #pragma unroll
        for (int r = 0; r < 4; ++r) {
          float alr = __shfl(al, quad * 4 + r);   // al for q = quad*4+r
          liacc[mt][r] *= alr;
          #pragma unroll
          for (int nt = 0; nt < 8; ++nt) oacc[mt][nt][r] *= alr;
        }
      }
      float nm = -mi[mt] * scale;
      #pragma unroll
      for (int nt = 0; nt < 4; ++nt)
        #pragma unroll
        for (int r = 0; r < 4; ++r)
          sacc[mt][nt][r] = exp2f(fmaf(sacc[mt][nt][r], scale, nm));
      // pack to f16x2 dwords: pd[nt][h] = (p[2h], p[2h+1]) for keys nt*16+quad*4+{2h,2h+1}
      uint32_t pd[4][2];
      #pragma unroll
      for (int nt = 0; nt < 4; ++nt) {
        f16x2 lo2, hi2;
        lo2[0] = (_Float16)sacc[mt][nt][0]; lo2[1] = (_Float16)sacc[mt][nt][1];
        hi2[0] = (_Float16)sacc[mt][nt][2]; hi2[1] = (_Float16)sacc[mt][nt][3];
        pd[nt][0] = __builtin_bit_cast(uint32_t, lo2);
        pd[nt][1] = __builtin_bit_cast(uint32_t, hi2);
      }
      // rebuild A-fragments: pfk[k2][j] = P[q=l15][key = k2*32 + quad*8 + j]
      f16x8 pfk[2];
      #pragma unroll
      for (int k2 = 0; k2 < 2; ++k2) {
        uint32_t w[4];
        #pragma unroll
        for (int h = 0; h < 2; ++h) {
          uint32_t a0v = (uint32_t)__shfl((int)pd[2 * k2][h],     idxA);
          uint32_t a1v = (uint32_t)__shfl((int)pd[2 * k2 + 1][h], idxA);
          w[h] = hiNt ? a1v : a0v;
          uint32_t b0v = (uint32_t)__shfl((int)pd[2 * k2][h],     idxB);
          uint32_t b1v = (uint32_t)__shfl((int)pd[2 * k2 + 1][h], idxB);
          w[2 + h] = hiNt ? b1v : b0v;
        }
        u32x4 wv = {w[0], w[1], w[2], w[3]};
        pfk[k2] = __builtin_bit_cast(f16x8, wv);
      }
      // ---- O[mt] += P[mt] V ; li[mt] += P[mt]*1 ----
      #pragma unroll
      for (int k2 = 0; k2 < 2; ++k2) {
        f16x8 vf[8];
        #pragma unroll
        for (int nt = 0; nt < 8; ++nt) {
          int rv = nt * 16 + l15;
          int pv = (k2 * 4 + quad) ^ (rv & 7);
          vf[nt] = *(const f16x8*)((const char*)Vs + rv * 128 + pv * 16);
        }
        __builtin_amdgcn_s_setprio(1);
        liacc[mt] = __builtin_amdgcn_mfma_f32_16x16x32_f16(pfk[k2], ones, liacc[mt], 0, 0, 0);
        #pragma unroll
        for (int nt = 0; nt < 8; ++nt)
          oacc[mt][nt] = __builtin_amdgcn_mfma_f32_16x16x32_f16(pfk[k2], vf[nt], oacc[mt][nt], 0, 0, 0);
        __builtin_amdgcn_s_setprio(0);
      }
    }

    // barrier B: all waves done reading V[kt]; drains K[kt+1] stage
    __syncthreads();
    if (kt + 1 < nkt) stageV(kt + 1);   // covered by next QK, drained at barrier A
  }

  // epilogue: O / l  (oacc/liacc row q = quad*4+r, col d = nt*16+l15)
  #pragma unroll
  for (int mt = 0; mt < 2; ++mt)
    #pragma unroll
    for (int r = 0; r < 4; ++r) {
      float inv = 1.0f / liacc[mt][r];
      size_t row = (size_t)b * S + qt * 128 + wave * 32 + mt * 16 + quad * 4 + r;
      #pragma unroll
      for (int nt = 0; nt < 8; ++nt)
        O[row * 4096 + hq * 128 + nt * 16 + l15] = (_Float16)(oacc[mt][nt][r] * inv);
    }
}

extern "C" void kernel_launch(void* const* d_in, const int* in_sizes, int n_in,
                              void* d_out, int out_size, void* d_ws, size_t ws_size,
                              hipStream_t stream) {
  const float* x  = (const float*)d_in[0];
  const float* wq = (const float*)d_in[1];
  const float* wk = (const float*)d_in[2];
  const float* wv = (const float*)d_in[3];
  const float* wo = (const float*)d_in[4];
  const int*   sp = (const int*)d_in[5];

  const int dim = 4096, kvdim = 1024;
  const int T = in_sizes[0] / dim;   // 4096 tokens (b*s)
  const int B = 2;
  const int S = T / B;               // 2048

  // workspace layout (fp16), total ~160 MiB
  _Float16* xb   = (_Float16*)d_ws;
  _Float16* wqb  = xb   + (size_t)T * dim;        // wq (4096 rows)
  _Float16* wkvb = wqb  + (size_t)dim * dim;      // wk (1024) then wv (1024), contiguous after wq
  _Float16* wob  = wkvb + (size_t)2 * kvdim * dim;
  _Float16* XQ   = wob  + (size_t)dim * dim;
  _Float16* XK   = XQ   + (size_t)T * dim;
  _Float16* VT   = XK   + (size_t)T * kvdim;
  _Float16* AO   = xb;               // alias: xb dead after projections

  // one launch: all five fp32->fp16 conversions
  cvt5_kernel<<<dim3(2048, 5), 256, 0, stream>>>(
      x, wq, wk, wv, wo,
      xb, wqb, wkvb, wkvb + (size_t)kvdim * dim, wob,
      (int)((size_t)T * dim / 4), (int)((size_t)dim * dim / 4),
      (int)((size_t)kvdim * dim / 4), (int)((size_t)kvdim * dim / 4),
      (int)((size_t)dim * dim / 4));

  // one launch: Q+K+V projections with fused RoPE on Q,K (wq|wk|wv contiguous)
  gemm_nt<4, 3><<<dim3((dim + 2 * kvdim) / 128, T / 128), 256, 0, stream>>>(
      xb, wqb, XQ, XK, VT, sp, T, dim + 2 * kvdim, dim, S - 1);

  // attention
  flash_kernel<<<dim3(S / 128, 32, B), 256, 0, stream>>>(XQ, XK, VT, AO, S, T);

  // output projection (fp32 out); MINW=4 -> 4 blocks/CU -> 1024 grid = 1 generation
  gemm_nt<2, 4><<<dim3(dim / 128, T / 128), 256, 0, stream>>>(
      AO, wob, d_out, nullptr, nullptr, nullptr, T, dim, dim, 0);
}

// Round 8
// 789.290 us; speedup vs baseline: 1.0633x; 1.0633x over previous
//
#include <hip/hip_runtime.h>
#include <cstdint>
#include <cstddef>

typedef _Float16 f16x8 __attribute__((ext_vector_type(8)));
typedef _Float16 f16x4 __attribute__((ext_vector_type(4)));
typedef _Float16 f16x2 __attribute__((ext_vector_type(2)));
typedef float    f32x4 __attribute__((ext_vector_type(4)));
typedef uint32_t u32x4 __attribute__((ext_vector_type(4)));

__device__ __forceinline__ void async16(const void* g, void* l) {
  __builtin_amdgcn_global_load_lds(
      (const __attribute__((address_space(1))) void*)g,
      (__attribute__((address_space(3))) void*)l, 16, 0, 0);
}

// ---------------- fused fp32 -> fp16 convert, 5 segments in one launch ----------------
__global__ void cvt5_kernel(const float* __restrict__ s0, const float* __restrict__ s1,
                            const float* __restrict__ s2, const float* __restrict__ s3,
                            const float* __restrict__ s4,
                            _Float16* __restrict__ d0, _Float16* __restrict__ d1,
                            _Float16* __restrict__ d2, _Float16* __restrict__ d3,
                            _Float16* __restrict__ d4,
                            int n0, int n1, int n2, int n3, int n4c) {
  const float* src; _Float16* dst; int n4;
  switch (blockIdx.y) {
    case 0:  src = s0; dst = d0; n4 = n0;  break;
    case 1:  src = s1; dst = d1; n4 = n1;  break;
    case 2:  src = s2; dst = d2; n4 = n2;  break;
    case 3:  src = s3; dst = d3; n4 = n3;  break;
    default: src = s4; dst = d4; n4 = n4c; break;
  }
  int i = blockIdx.x * blockDim.x + threadIdx.x;
  int stride = gridDim.x * blockDim.x;
  for (; i < n4; i += stride) {
    float4 f = ((const float4*)src)[i];
    f16x4 o;
    o[0] = (_Float16)f.x; o[1] = (_Float16)f.y;
    o[2] = (_Float16)f.z; o[3] = (_Float16)f.w;
    ((f16x4*)dst)[i] = o;
  }
}

// ---------------- NT GEMM: C = A(M,K) * B(N,K)^T ----------------
// OUT_MODE 2: f32 C row-major (ld=N).
// MINW: min waves/EU for launch_bounds. BOTH gemms use 3 — R7 showed MINW=4
//   (forcing VGPR<=128) regresses ~50us, same spill mechanism as R2.
// OUT_MODE 4: fused QKV epilogue WITH RoPE on Q and K:
//   cols [0,4096) -> roped f16 XQ (ld=4096); [4096,5120) -> roped f16 XK (ld=1024);
//   [5120,6144) -> f16 VT transposed (ld=M), no rope.
//   RoPE on acc in-register: pair (even d, odd d) sits in lanes (l15, l15^1);
//   fi=(col&127)>>1, s=row&sMask; even: self*cs - other*sn; odd: other*sn + self*cs.
template<int OUT_MODE, int MINW>
__global__ __launch_bounds__(256, MINW)
void gemm_nt(const _Float16* __restrict__ A, const _Float16* __restrict__ B,
             void* __restrict__ Cp, void* __restrict__ Cp2, void* __restrict__ Cp3,
             const int* __restrict__ sp,
             int M, int N, int K, int sMask) {
  __shared__ __align__(16) _Float16 As[128 * 64];
  __shared__ __align__(16) _Float16 Bs[128 * 64];
  const int tid  = threadIdx.x;
  const int wave = tid >> 6, lane = tid & 63;
  const int l15  = lane & 15, quad = lane >> 4;
  const int m0 = blockIdx.y * 128, n0 = blockIdx.x * 128;
  const int wm = (wave >> 1) * 64, wn = (wave & 1) * 64;
  f32x4 acc[4][4] = {};
  const int cbase = wave * 256;

  for (int kb = 0; kb < K; kb += 64) {
    // stage A,B tiles (128x64 f16 each) via global_load_lds, XOR chunk swizzle
    #pragma unroll
    for (int i = 0; i < 4; ++i) {
      int base = cbase + i * 64;
      int idx  = base + lane;          // chunk 0..1023
      int row  = idx >> 3, pos = idx & 7;
      int c    = pos ^ (row & 7);
      async16(A + (size_t)(m0 + row) * K + kb + c * 8, (char*)As + base * 16);
      async16(B + (size_t)(n0 + row) * K + kb + c * 8, (char*)Bs + base * 16);
    }
    __syncthreads();
    #pragma unroll
    for (int ks = 0; ks < 2; ++ks) {
      f16x8 af[4], bfv[4];
      #pragma unroll
      for (int t = 0; t < 4; ++t) {
        int ra = wm + t * 16 + l15;
        int pa = (ks * 4 + quad) ^ (ra & 7);
        af[t] = *(const f16x8*)((const char*)As + ra * 128 + pa * 16);
        int rb = wn + t * 16 + l15;
        int pb = (ks * 4 + quad) ^ (rb & 7);
        bfv[t] = *(const f16x8*)((const char*)Bs + rb * 128 + pb * 16);
      }
      #pragma unroll
      for (int mt = 0; mt < 4; ++mt)
        #pragma unroll
        for (int nt = 0; nt < 4; ++nt)
          acc[mt][nt] = __builtin_amdgcn_mfma_f32_16x16x32_f16(af[mt], bfv[nt], acc[mt][nt], 0, 0, 0);
    }
    __syncthreads();
  }

  if constexpr (OUT_MODE == 2) {
    float* Cf = (float*)Cp;
    #pragma unroll
    for (int mt = 0; mt < 4; ++mt)
      #pragma unroll
      for (int r = 0; r < 4; ++r) {
        size_t row = (size_t)(m0 + wm + mt * 16 + quad * 4 + r);
        #pragma unroll
        for (int nt = 0; nt < 4; ++nt)
          Cf[row * N + n0 + wn + nt * 16 + l15] = acc[mt][nt][r];
      }
  } else if constexpr (OUT_MODE == 4) {
    if (n0 < 5120) {           // Q or K projection: rope + f16 store
      const bool isQ = (n0 < 4096);
      _Float16* Cb = isQ ? (_Float16*)Cp : (_Float16*)Cp2;
      const int ld   = isQ ? 4096 : 1024;
      const int cof  = isQ ? 0 : 4096;
      const int start = *sp;
      const bool odd = (l15 & 1) != 0;
      #pragma unroll
      for (int mt = 0; mt < 4; ++mt)
        #pragma unroll
        for (int r = 0; r < 4; ++r) {
          int row = m0 + wm + mt * 16 + quad * 4 + r;
          float pos = (float)(start + (row & sMask));
          #pragma unroll
          for (int nt = 0; nt < 4; ++nt) {
            int col = n0 - cof + wn + nt * 16 + l15;
            int fi  = (col & 127) >> 1;
            float ang = pos * exp2f(-0.20762050593046014f * (float)fi);
            float sn, cs;
            __sincosf(ang, &sn, &cs);
            float self  = acc[mt][nt][r];
            float other = __shfl_xor(self, 1);
            float out = odd ? (other * sn + self * cs)
                            : (self * cs - other * sn);
            Cb[(size_t)row * ld + col] = (_Float16)out;
          }
        }
    } else {                   // V projection: store transposed (feature-major), no rope
      _Float16* Ct = (_Float16*)Cp3;
      #pragma unroll
      for (int mt = 0; mt < 4; ++mt)
        #pragma unroll
        for (int nt = 0; nt < 4; ++nt) {
          size_t crow = (size_t)(n0 - 5120 + wn + nt * 16 + l15);
          size_t ccol = (size_t)(m0 + wm + mt * 16 + quad * 4);
          f16x4 t;
          t[0] = (_Float16)acc[mt][nt][0]; t[1] = (_Float16)acc[mt][nt][1];
          t[2] = (_Float16)acc[mt][nt][2]; t[3] = (_Float16)acc[mt][nt][3];
          *(f16x4*)(Ct + crow * M + ccol) = t;
        }
    }
  }
}

// ---------------- flash attention, non-causal, GQA 4:1 ----------------
// R5/R6-verified core (swapped QK^T, in-register P rebuild, 32KB LDS, 234us,
// MfmaUtil 27.8). R7's per-mt SM->PV interleave REVERTED: measured -18us
// (vf re-read + tighter dep chain beat the hoped MFMA/VALU overlap).
__global__ __launch_bounds__(256, 2)
void flash_kernel(const _Float16* __restrict__ Q, const _Float16* __restrict__ Kg,
                  const _Float16* __restrict__ Vt, _Float16* __restrict__ O,
                  int S, int T) {
  __shared__ __align__(16) _Float16 Kt[64 * 128];   // [key][d], swizzled
  __shared__ __align__(16) _Float16 Vs[128 * 64];   // [d][key], swizzled
  const int tid  = threadIdx.x;
  const int wave = tid >> 6, lane = tid & 63;
  const int l15  = lane & 15, quad = lane >> 4;
  const int qt = blockIdx.x, hq = blockIdx.y, b = blockIdx.z;
  const int kvh = hq >> 2;
  const float scale = 0.12751744f;   // log2(e)/sqrt(128): softmax in exp2 domain

  // Q fragments in registers: wave owns 32 q-rows (q = mt*16 + l15)
  f16x8 qf[2][4];
  #pragma unroll
  for (int mt = 0; mt < 2; ++mt)
    #pragma unroll
    for (int ks = 0; ks < 4; ++ks) {
      size_t row = (size_t)b * S + qt * 128 + wave * 32 + mt * 16 + l15;
      qf[mt][ks] = *(const f16x8*)(Q + row * 4096 + hq * 128 + ks * 32 + quad * 8);
    }

  const f16x8 ones = {(_Float16)1, (_Float16)1, (_Float16)1, (_Float16)1,
                      (_Float16)1, (_Float16)1, (_Float16)1, (_Float16)1};

  f32x4 oacc[2][8] = {};
  f32x4 liacc[2] = {};              // row-sums via MFMA(P, ones): q = quad*4+r
  float mi[2] = {-1e30f, -1e30f};   // running max, lane-local (q = l15)

  const int nkt = S >> 6;

  auto stageK = [&](int kt) {
    #pragma unroll
    for (int i = 0; i < 4; ++i) {
      int base = wave * 256 + i * 64;
      int idx  = base + lane;
      int row = idx >> 4, pos = idx & 15, c = pos ^ (row & 15);
      async16(Kg + (size_t)(b * S + kt * 64 + row) * 1024 + kvh * 128 + c * 8,
              (char*)Kt + base * 16);
    }
  };
  auto stageV = [&](int kt) {
    #pragma unroll
    for (int i = 0; i < 4; ++i) {
      int base = wave * 256 + i * 64;
      int idx  = base + lane;
      int row = idx >> 3, pos = idx & 7, c = pos ^ (row & 7);
      async16(Vt + (size_t)(kvh * 128 + row) * T + b * S + kt * 64 + c * 8,
              (char*)Vs + base * 16);
    }
  };

  stageK(0); stageV(0);
  __syncthreads();           // drain prologue

  // P redistribution source lanes (quad-group permute within same l15)
  const int idxA = l15 + (((quad * 2) & 3) << 4);      // elems j0..3
  const int idxB = l15 + (((quad * 2 + 1) & 3) << 4);  // elems j4..7
  const bool hiNt = (quad >> 1) != 0;                  // nt_s = 2*k2 + (quad>>1)

  for (int kt = 0; kt < nkt; ++kt) {
    // ---- S^T = K Q^T: sacc[mt][nt] holds S[key=nt*16+quad*4+r][q=mt*16+l15] ----
    f32x4 sacc[2][4] = {};
    #pragma unroll
    for (int ks = 0; ks < 4; ++ks) {
      f16x8 kf[4];
      #pragma unroll
      for (int nt = 0; nt < 4; ++nt) {
        int rk = nt * 16 + l15;
        int pp = (ks * 4 + quad) ^ (rk & 15);
        kf[nt] = *(const f16x8*)((const char*)Kt + rk * 256 + pp * 16);
      }
      __builtin_amdgcn_s_setprio(1);
      #pragma unroll
      for (int mt = 0; mt < 2; ++mt)
        #pragma unroll
        for (int nt = 0; nt < 4; ++nt)
          sacc[mt][nt] = __builtin_amdgcn_mfma_f32_16x16x32_f16(kf[nt], qf[mt][ks], sacc[mt][nt], 0, 0, 0);
      __builtin_amdgcn_s_setprio(0);
    }

    // barrier A: all waves done reading K[kt]; drains V[kt] stage (issued last iter)
    __syncthreads();
    if (kt + 1 < nkt) stageK(kt + 1);   // covered by softmax+PV, drained at barrier B

    // ---- softmax + in-register P -> A-fragment rebuild (both halves) ----
    f16x8 pf[2][2];
    #pragma unroll
    for (int mt = 0; mt < 2; ++mt) {
      // lane-local max over 16 keys (balanced tree), then 2-step quad butterfly
      float a0 = fmaxf(fmaxf(sacc[mt][0][0], sacc[mt][0][1]), fmaxf(sacc[mt][0][2], sacc[mt][0][3]));
      float a1 = fmaxf(fmaxf(sacc[mt][1][0], sacc[mt][1][1]), fmaxf(sacc[mt][1][2], sacc[mt][1][3]));
      float a2 = fmaxf(fmaxf(sacc[mt][2][0], sacc[mt][2][1]), fmaxf(sacc[mt][2][2], sacc[mt][2][3]));
      float a3 = fmaxf(fmaxf(sacc[mt][3][0], sacc[mt][3][1]), fmaxf(sacc[mt][3][2], sacc[mt][3][3]));
      float mx = fmaxf(fmaxf(a0, a1), fmaxf(a2, a3));
      mx = fmaxf(mx, __shfl_xor(mx, 16));
      mx = fmaxf(mx, __shfl_xor(mx, 32));
      // defer-max: rescale only when running max grew materially (24 raw ~ 2^3)
      if (__any(mx > mi[mt] + 24.0f)) {
        float mnew = fmaxf(mi[mt], mx);
        float al = exp2f((mi[mt] - mnew) * scale);
        mi[mt] = mnew;
        #pragma unroll
        for (int r = 0; r < 4; ++r) {
          float alr = __shfl(al, quad * 4 + r);   // al for q = quad*4+r
          liacc[mt][r] *= alr;
          #pragma unroll
          for (int nt = 0; nt < 8; ++nt) oacc[mt][nt][r] *= alr;
        }
      }
      float nm = -mi[mt] * scale;
      #pragma unroll
      for (int nt = 0; nt < 4; ++nt)
        #pragma unroll
        for (int r = 0; r < 4; ++r)
          sacc[mt][nt][r] = exp2f(fmaf(sacc[mt][nt][r], scale, nm));
      // pack to f16x2 dwords: pd[nt][h] = (p[2h], p[2h+1]) for keys nt*16+quad*4+{2h,2h+1}
      uint32_t pd[4][2];
      #pragma unroll
      for (int nt = 0; nt < 4; ++nt) {
        f16x2 lo2, hi2;
        lo2[0] = (_Float16)sacc[mt][nt][0]; lo2[1] = (_Float16)sacc[mt][nt][1];
        hi2[0] = (_Float16)sacc[mt][nt][2]; hi2[1] = (_Float16)sacc[mt][nt][3];
        pd[nt][0] = __builtin_bit_cast(uint32_t, lo2);
        pd[nt][1] = __builtin_bit_cast(uint32_t, hi2);
      }
      // rebuild A-fragments: pf[mt][k2][j] = P[q=l15][key = k2*32 + quad*8 + j]
      #pragma unroll
      for (int k2 = 0; k2 < 2; ++k2) {
        uint32_t w[4];
        #pragma unroll
        for (int h = 0; h < 2; ++h) {
          uint32_t a0v = (uint32_t)__shfl((int)pd[2 * k2][h],     idxA);
          uint32_t a1v = (uint32_t)__shfl((int)pd[2 * k2 + 1][h], idxA);
          w[h] = hiNt ? a1v : a0v;
          uint32_t b0v = (uint32_t)__shfl((int)pd[2 * k2][h],     idxB);
          uint32_t b1v = (uint32_t)__shfl((int)pd[2 * k2 + 1][h], idxB);
          w[2 + h] = hiNt ? b1v : b0v;
        }
        u32x4 wv = {w[0], w[1], w[2], w[3]};
        pf[mt][k2] = __builtin_bit_cast(f16x8, wv);
      }
    }

    // ---- O += P V ; li += P*1 ----
    #pragma unroll
    for (int k2 = 0; k2 < 2; ++k2) {
      f16x8 vf[8];
      #pragma unroll
      for (int nt = 0; nt < 8; ++nt) {
        int rv = nt * 16 + l15;
        int pv = (k2 * 4 + quad) ^ (rv & 7);
        vf[nt] = *(const f16x8*)((const char*)Vs + rv * 128 + pv * 16);
      }
      __builtin_amdgcn_s_setprio(1);
      #pragma unroll
      for (int mt = 0; mt < 2; ++mt)
        liacc[mt] = __builtin_amdgcn_mfma_f32_16x16x32_f16(pf[mt][k2], ones, liacc[mt], 0, 0, 0);
      #pragma unroll
      for (int mt = 0; mt < 2; ++mt)
        #pragma unroll
        for (int nt = 0; nt < 8; ++nt)
          oacc[mt][nt] = __builtin_amdgcn_mfma_f32_16x16x32_f16(pf[mt][k2], vf[nt], oacc[mt][nt], 0, 0, 0);
      __builtin_amdgcn_s_setprio(0);
    }

    // barrier B: all waves done reading V[kt]; drains K[kt+1] stage
    __syncthreads();
    if (kt + 1 < nkt) stageV(kt + 1);   // covered by next QK, drained at barrier A
  }

  // epilogue: O / l  (oacc/liacc row q = quad*4+r, col d = nt*16+l15)
  #pragma unroll
  for (int mt = 0; mt < 2; ++mt)
    #pragma unroll
    for (int r = 0; r < 4; ++r) {
      float inv = 1.0f / liacc[mt][r];
      size_t row = (size_t)b * S + qt * 128 + wave * 32 + mt * 16 + quad * 4 + r;
      #pragma unroll
      for (int nt = 0; nt < 8; ++nt)
        O[row * 4096 + hq * 128 + nt * 16 + l15] = (_Float16)(oacc[mt][nt][r] * inv);
    }
}

extern "C" void kernel_launch(void* const* d_in, const int* in_sizes, int n_in,
                              void* d_out, int out_size, void* d_ws, size_t ws_size,
                              hipStream_t stream) {
  const float* x  = (const float*)d_in[0];
  const float* wq = (const float*)d_in[1];
  const float* wk = (const float*)d_in[2];
  const float* wv = (const float*)d_in[3];
  const float* wo = (const float*)d_in[4];
  const int*   sp = (const int*)d_in[5];

  const int dim = 4096, kvdim = 1024;
  const int T = in_sizes[0] / dim;   // 4096 tokens (b*s)
  const int B = 2;
  const int S = T / B;               // 2048

  // workspace layout (fp16), total ~160 MiB
  _Float16* xb   = (_Float16*)d_ws;
  _Float16* wqb  = xb   + (size_t)T * dim;        // wq (4096 rows)
  _Float16* wkvb = wqb  + (size_t)dim * dim;      // wk (1024) then wv (1024), contiguous after wq
  _Float16* wob  = wkvb + (size_t)2 * kvdim * dim;
  _Float16* XQ   = wob  + (size_t)dim * dim;
  _Float16* XK   = XQ   + (size_t)T * dim;
  _Float16* VT   = XK   + (size_t)T * kvdim;
  _Float16* AO   = xb;               // alias: xb dead after projections

  // one launch: all five fp32->fp16 conversions
  cvt5_kernel<<<dim3(2048, 5), 256, 0, stream>>>(
      x, wq, wk, wv, wo,
      xb, wqb, wkvb, wkvb + (size_t)kvdim * dim, wob,
      (int)((size_t)T * dim / 4), (int)((size_t)dim * dim / 4),
      (int)((size_t)kvdim * dim / 4), (int)((size_t)kvdim * dim / 4),
      (int)((size_t)dim * dim / 4));

  // one launch: Q+K+V projections with fused RoPE on Q,K (wq|wk|wv contiguous)
  gemm_nt<4, 3><<<dim3((dim + 2 * kvdim) / 128, T / 128), 256, 0, stream>>>(
      xb, wqb, XQ, XK, VT, sp, T, dim + 2 * kvdim, dim, S - 1);

  // attention
  flash_kernel<<<dim3(S / 128, 32, B), 256, 0, stream>>>(XQ, XK, VT, AO, S, T);

  // output projection (fp32 out), MINW=3 (MINW=4 spilled, R7)
  gemm_nt<2, 3><<<dim3(dim / 128, T / 128), 256, 0, stream>>>(
      AO, wob, d_out, nullptr, nullptr, nullptr, T, dim, dim, 0);
}

// Round 9
// 753.167 us; speedup vs baseline: 1.1143x; 1.0480x over previous
//
#include <hip/hip_runtime.h>
#include <cstdint>
#include <cstddef>

typedef _Float16 f16x8 __attribute__((ext_vector_type(8)));
typedef _Float16 f16x4 __attribute__((ext_vector_type(4)));
typedef _Float16 f16x2 __attribute__((ext_vector_type(2)));
typedef float    f32x4 __attribute__((ext_vector_type(4)));
typedef uint32_t u32x4 __attribute__((ext_vector_type(4)));

__device__ __forceinline__ void async16(const void* g, void* l) {
  __builtin_amdgcn_global_load_lds(
      (const __attribute__((address_space(1))) void*)g,
      (__attribute__((address_space(3))) void*)l, 16, 0, 0);
}

// ---------------- fused fp32 -> fp16 convert, 5 segments in one launch ----------------
__global__ void cvt5_kernel(const float* __restrict__ s0, const float* __restrict__ s1,
                            const float* __restrict__ s2, const float* __restrict__ s3,
                            const float* __restrict__ s4,
                            _Float16* __restrict__ d0, _Float16* __restrict__ d1,
                            _Float16* __restrict__ d2, _Float16* __restrict__ d3,
                            _Float16* __restrict__ d4,
                            int n0, int n1, int n2, int n3, int n4c) {
  const float* src; _Float16* dst; int n4;
  switch (blockIdx.y) {
    case 0:  src = s0; dst = d0; n4 = n0;  break;
    case 1:  src = s1; dst = d1; n4 = n1;  break;
    case 2:  src = s2; dst = d2; n4 = n2;  break;
    case 3:  src = s3; dst = d3; n4 = n3;  break;
    default: src = s4; dst = d4; n4 = n4c; break;
  }
  int i = blockIdx.x * blockDim.x + threadIdx.x;
  int stride = gridDim.x * blockDim.x;
  for (; i < n4; i += stride) {
    float4 f = ((const float4*)src)[i];
    f16x4 o;
    o[0] = (_Float16)f.x; o[1] = (_Float16)f.y;
    o[2] = (_Float16)f.z; o[3] = (_Float16)f.w;
    ((f16x4*)dst)[i] = o;
  }
}

// ---------------- RoPE, interleaved pairs, in place, XQ+XK in one launch ----------------
// R8 A/B: fusing rope into the GEMM epilogue cost +26us (redundant per-lane trig
// in a compute-bound epilogue). Standalone kernel is ~12us. Keep standalone.
__global__ void rope2_kernel(_Float16* __restrict__ XQ, _Float16* __restrict__ XK,
                             const int* __restrict__ sp, int sMask,
                             int nPairsQ, int nPairsK) {
  _Float16* X; int ppShift, nPairs;
  if (blockIdx.y == 0) { X = XQ; ppShift = 11; nPairs = nPairsQ; }
  else                 { X = XK; ppShift = 9;  nPairs = nPairsK; }
  int i = blockIdx.x * blockDim.x + threadIdx.x;
  int stride = gridDim.x * blockDim.x;
  int start = *sp;
  for (int p = i; p < nPairs; p += stride) {
    int row = p >> ppShift;
    int pc  = p & ((1 << ppShift) - 1);
    int fi  = pc & 63;                 // pair index within head (d/2 = 64)
    int s   = row & sMask;             // row = b*S + s
    float ang = (float)(start + s) * exp2f(-0.20762050593046014f * (float)fi);
    float sn, cs;
    __sincosf(ang, &sn, &cs);
    uint32_t u = ((uint32_t*)X)[p];
    f16x2 v = __builtin_bit_cast(f16x2, u);
    float x1 = (float)v[0], x2 = (float)v[1];
    v[0] = (_Float16)(x1 * cs - x2 * sn);
    v[1] = (_Float16)(x1 * sn + x2 * cs);
    ((uint32_t*)X)[p] = __builtin_bit_cast(uint32_t, v);
  }
}

// ---------------- NT GEMM, 128x128 tile: QKV projection ----------------
// Fused epilogue: cols [0,4096) -> f16 XQ (ld=4096); [4096,5120) -> f16 XK
// (ld=1024); [5120,6144) -> f16 VT transposed (ld=M). Grid 1536 = 2 exact
// generations at 3 blocks/CU (no tail).
__global__ __launch_bounds__(256, 3)
void gemm_qkv(const _Float16* __restrict__ A, const _Float16* __restrict__ B,
              _Float16* __restrict__ Cq, _Float16* __restrict__ Ck,
              _Float16* __restrict__ Cvt,
              int M, int N, int K) {
  __shared__ __align__(16) _Float16 As[128 * 64];
  __shared__ __align__(16) _Float16 Bs[128 * 64];
  const int tid  = threadIdx.x;
  const int wave = tid >> 6, lane = tid & 63;
  const int l15  = lane & 15, quad = lane >> 4;
  const int m0 = blockIdx.y * 128, n0 = blockIdx.x * 128;
  const int wm = (wave >> 1) * 64, wn = (wave & 1) * 64;
  f32x4 acc[4][4] = {};
  const int cbase = wave * 256;

  for (int kb = 0; kb < K; kb += 64) {
    #pragma unroll
    for (int i = 0; i < 4; ++i) {
      int base = cbase + i * 64;
      int idx  = base + lane;          // chunk 0..1023
      int row  = idx >> 3, pos = idx & 7;
      int c    = pos ^ (row & 7);
      async16(A + (size_t)(m0 + row) * K + kb + c * 8, (char*)As + base * 16);
      async16(B + (size_t)(n0 + row) * K + kb + c * 8, (char*)Bs + base * 16);
    }
    __syncthreads();
    #pragma unroll
    for (int ks = 0; ks < 2; ++ks) {
      f16x8 af[4], bfv[4];
      #pragma unroll
      for (int t = 0; t < 4; ++t) {
        int ra = wm + t * 16 + l15;
        int pa = (ks * 4 + quad) ^ (ra & 7);
        af[t] = *(const f16x8*)((const char*)As + ra * 128 + pa * 16);
        int rb = wn + t * 16 + l15;
        int pb = (ks * 4 + quad) ^ (rb & 7);
        bfv[t] = *(const f16x8*)((const char*)Bs + rb * 128 + pb * 16);
      }
      #pragma unroll
      for (int mt = 0; mt < 4; ++mt)
        #pragma unroll
        for (int nt = 0; nt < 4; ++nt)
          acc[mt][nt] = __builtin_amdgcn_mfma_f32_16x16x32_f16(af[mt], bfv[nt], acc[mt][nt], 0, 0, 0);
    }
    __syncthreads();
  }

  if (n0 < 4096) {           // Q projection: f16, ld = 4096
    #pragma unroll
    for (int mt = 0; mt < 4; ++mt)
      #pragma unroll
      for (int r = 0; r < 4; ++r) {
        size_t row = (size_t)(m0 + wm + mt * 16 + quad * 4 + r);
        #pragma unroll
        for (int nt = 0; nt < 4; ++nt)
          Cq[row * 4096 + n0 + wn + nt * 16 + l15] = (_Float16)acc[mt][nt][r];
      }
  } else if (n0 < 5120) {    // K projection: f16, ld = 1024
    #pragma unroll
    for (int mt = 0; mt < 4; ++mt)
      #pragma unroll
      for (int r = 0; r < 4; ++r) {
        size_t row = (size_t)(m0 + wm + mt * 16 + quad * 4 + r);
        #pragma unroll
        for (int nt = 0; nt < 4; ++nt)
          Ck[row * 1024 + (n0 - 4096) + wn + nt * 16 + l15] = (_Float16)acc[mt][nt][r];
      }
  } else {                   // V projection: store transposed (feature-major)
    #pragma unroll
    for (int mt = 0; mt < 4; ++mt)
      #pragma unroll
      for (int nt = 0; nt < 4; ++nt) {
        size_t crow = (size_t)(n0 - 5120 + wn + nt * 16 + l15);
        size_t ccol = (size_t)(m0 + wm + mt * 16 + quad * 4);
        f16x4 t;
        t[0] = (_Float16)acc[mt][nt][0]; t[1] = (_Float16)acc[mt][nt][1];
        t[2] = (_Float16)acc[mt][nt][2]; t[3] = (_Float16)acc[mt][nt][3];
        *(f16x4*)(Cvt + crow * M + ccol) = t;
      }
  }
}

// ---------------- NT GEMM, 128x256 tile: O projection (f32 out) ----------------
// m105-measured tile point: 823 TF ref-checked at 4096^3 on this structure.
// Grid (4096/256)x(4096/128) = 512 blocks; ~200 VGPR + 48KB LDS -> 2 blocks/CU
// -> 512 = EXACTLY one generation (kills the 1.33-gen tail that made the 128^2
// O-proj run at effective ~600 TF). launch_bounds(256,2): full VGPR budget.
__global__ __launch_bounds__(256, 2)
void gemm_wide(const _Float16* __restrict__ A, const _Float16* __restrict__ B,
               float* __restrict__ C, int M, int N, int K) {
  __shared__ __align__(16) _Float16 As[128 * 64];   // 16 KB
  __shared__ __align__(16) _Float16 Bs[256 * 64];   // 32 KB
  const int tid  = threadIdx.x;
  const int wave = tid >> 6, lane = tid & 63;
  const int l15  = lane & 15, quad = lane >> 4;
  const int m0 = blockIdx.y * 128, n0 = blockIdx.x * 256;
  const int wm = (wave >> 1) * 64, wn = (wave & 1) * 128;
  f32x4 acc[4][8] = {};
  const int cbaseA = wave * 256;   // 1024 A-chunks over 4 waves
  const int cbaseB = wave * 512;   // 2048 B-chunks over 4 waves

  for (int kb = 0; kb < K; kb += 64) {
    #pragma unroll
    for (int i = 0; i < 4; ++i) {
      int base = cbaseA + i * 64;
      int idx  = base + lane;
      int row  = idx >> 3, pos = idx & 7;
      int c    = pos ^ (row & 7);
      async16(A + (size_t)(m0 + row) * K + kb + c * 8, (char*)As + base * 16);
    }
    #pragma unroll
    for (int i = 0; i < 8; ++i) {
      int base = cbaseB + i * 64;
      int idx  = base + lane;
      int row  = idx >> 3, pos = idx & 7;
      int c    = pos ^ (row & 7);
      async16(B + (size_t)(n0 + row) * K + kb + c * 8, (char*)Bs + base * 16);
    }
    __syncthreads();
    #pragma unroll
    for (int ks = 0; ks < 2; ++ks) {
      f16x8 af[4], bfv[8];
      #pragma unroll
      for (int t = 0; t < 4; ++t) {
        int ra = wm + t * 16 + l15;
        int pa = (ks * 4 + quad) ^ (ra & 7);
        af[t] = *(const f16x8*)((const char*)As + ra * 128 + pa * 16);
      }
      #pragma unroll
      for (int t = 0; t < 8; ++t) {
        int rb = wn + t * 16 + l15;
        int pb = (ks * 4 + quad) ^ (rb & 7);
        bfv[t] = *(const f16x8*)((const char*)Bs + rb * 128 + pb * 16);
      }
      #pragma unroll
      for (int mt = 0; mt < 4; ++mt)
        #pragma unroll
        for (int nt = 0; nt < 8; ++nt)
          acc[mt][nt] = __builtin_amdgcn_mfma_f32_16x16x32_f16(af[mt], bfv[nt], acc[mt][nt], 0, 0, 0);
    }
    __syncthreads();
  }

  #pragma unroll
  for (int mt = 0; mt < 4; ++mt)
    #pragma unroll
    for (int r = 0; r < 4; ++r) {
      size_t row = (size_t)(m0 + wm + mt * 16 + quad * 4 + r);
      #pragma unroll
      for (int nt = 0; nt < 8; ++nt)
        C[row * N + n0 + wn + nt * 16 + l15] = acc[mt][nt][r];
    }
}

// ---------------- flash attention, non-causal, GQA 4:1 ----------------
// R5/R6-verified core (swapped QK^T, in-register P rebuild, 32KB LDS, 234us,
// MfmaUtil 27.8). R7's per-mt SM->PV interleave stays REVERTED (-18us).
__global__ __launch_bounds__(256, 2)
void flash_kernel(const _Float16* __restrict__ Q, const _Float16* __restrict__ Kg,
                  const _Float16* __restrict__ Vt, _Float16* __restrict__ O,
                  int S, int T) {
  __shared__ __align__(16) _Float16 Kt[64 * 128];   // [key][d], swizzled
  __shared__ __align__(16) _Float16 Vs[128 * 64];   // [d][key], swizzled
  const int tid  = threadIdx.x;
  const int wave = tid >> 6, lane = tid & 63;
  const int l15  = lane & 15, quad = lane >> 4;
  const int qt = blockIdx.x, hq = blockIdx.y, b = blockIdx.z;
  const int kvh = hq >> 2;
  const float scale = 0.12751744f;   // log2(e)/sqrt(128): softmax in exp2 domain

  // Q fragments in registers: wave owns 32 q-rows (q = mt*16 + l15)
  f16x8 qf[2][4];
  #pragma unroll
  for (int mt = 0; mt < 2; ++mt)
    #pragma unroll
    for (int ks = 0; ks < 4; ++ks) {
      size_t row = (size_t)b * S + qt * 128 + wave * 32 + mt * 16 + l15;
      qf[mt][ks] = *(const f16x8*)(Q + row * 4096 + hq * 128 + ks * 32 + quad * 8);
    }

  const f16x8 ones = {(_Float16)1, (_Float16)1, (_Float16)1, (_Float16)1,
                      (_Float16)1, (_Float16)1, (_Float16)1, (_Float16)1};

  f32x4 oacc[2][8] = {};
  f32x4 liacc[2] = {};              // row-sums via MFMA(P, ones): q = quad*4+r
  float mi[2] = {-1e30f, -1e30f};   // running max, lane-local (q = l15)

  const int nkt = S >> 6;

  auto stageK = [&](int kt) {
    #pragma unroll
    for (int i = 0; i < 4; ++i) {
      int base = wave * 256 + i * 64;
      int idx  = base + lane;
      int row = idx >> 4, pos = idx & 15, c = pos ^ (row & 15);
      async16(Kg + (size_t)(b * S + kt * 64 + row) * 1024 + kvh * 128 + c * 8,
              (char*)Kt + base * 16);
    }
  };
  auto stageV = [&](int kt) {
    #pragma unroll
    for (int i = 0; i < 4; ++i) {
      int base = wave * 256 + i * 64;
      int idx  = base + lane;
      int row = idx >> 3, pos = idx & 7, c = pos ^ (row & 7);
      async16(Vt + (size_t)(kvh * 128 + row) * T + b * S + kt * 64 + c * 8,
              (char*)Vs + base * 16);
    }
  };

  stageK(0); stageV(0);
  __syncthreads();           // drain prologue

  // P redistribution source lanes (quad-group permute within same l15)
  const int idxA = l15 + (((quad * 2) & 3) << 4);      // elems j0..3
  const int idxB = l15 + (((quad * 2 + 1) & 3) << 4);  // elems j4..7
  const bool hiNt = (quad >> 1) != 0;                  // nt_s = 2*k2 + (quad>>1)

  for (int kt = 0; kt < nkt; ++kt) {
    // ---- S^T = K Q^T: sacc[mt][nt] holds S[key=nt*16+quad*4+r][q=mt*16+l15] ----
    f32x4 sacc[2][4] = {};
    #pragma unroll
    for (int ks = 0; ks < 4; ++ks) {
      f16x8 kf[4];
      #pragma unroll
      for (int nt = 0; nt < 4; ++nt) {
        int rk = nt * 16 + l15;
        int pp = (ks * 4 + quad) ^ (rk & 15);
        kf[nt] = *(const f16x8*)((const char*)Kt + rk * 256 + pp * 16);
      }
      __builtin_amdgcn_s_setprio(1);
      #pragma unroll
      for (int mt = 0; mt < 2; ++mt)
        #pragma unroll
        for (int nt = 0; nt < 4; ++nt)
          sacc[mt][nt] = __builtin_amdgcn_mfma_f32_16x16x32_f16(kf[nt], qf[mt][ks], sacc[mt][nt], 0, 0, 0);
      __builtin_amdgcn_s_setprio(0);
    }

    // barrier A: all waves done reading K[kt]; drains V[kt] stage (issued last iter)
    __syncthreads();
    if (kt + 1 < nkt) stageK(kt + 1);   // covered by softmax+PV, drained at barrier B

    // ---- softmax + in-register P -> A-fragment rebuild (both halves) ----
    f16x8 pf[2][2];
    #pragma unroll
    for (int mt = 0; mt < 2; ++mt) {
      // lane-local max over 16 keys (balanced tree), then 2-step quad butterfly
      float a0 = fmaxf(fmaxf(sacc[mt][0][0], sacc[mt][0][1]), fmaxf(sacc[mt][0][2], sacc[mt][0][3]));
      float a1 = fmaxf(fmaxf(sacc[mt][1][0], sacc[mt][1][1]), fmaxf(sacc[mt][1][2], sacc[mt][1][3]));
      float a2 = fmaxf(fmaxf(sacc[mt][2][0], sacc[mt][2][1]), fmaxf(sacc[mt][2][2], sacc[mt][2][3]));
      float a3 = fmaxf(fmaxf(sacc[mt][3][0], sacc[mt][3][1]), fmaxf(sacc[mt][3][2], sacc[mt][3][3]));
      float mx = fmaxf(fmaxf(a0, a1), fmaxf(a2, a3));
      mx = fmaxf(mx, __shfl_xor(mx, 16));
      mx = fmaxf(mx, __shfl_xor(mx, 32));
      // defer-max: rescale only when running max grew materially (24 raw ~ 2^3)
      if (__any(mx > mi[mt] + 24.0f)) {
        float mnew = fmaxf(mi[mt], mx);
        float al = exp2f((mi[mt] - mnew) * scale);
        mi[mt] = mnew;
        #pragma unroll
        for (int r = 0; r < 4; ++r) {
          float alr = __shfl(al, quad * 4 + r);   // al for q = quad*4+r
          liacc[mt][r] *= alr;
          #pragma unroll
          for (int nt = 0; nt < 8; ++nt) oacc[mt][nt][r] *= alr;
        }
      }
      float nm = -mi[mt] * scale;
      #pragma unroll
      for (int nt = 0; nt < 4; ++nt)
        #pragma unroll
        for (int r = 0; r < 4; ++r)
          sacc[mt][nt][r] = exp2f(fmaf(sacc[mt][nt][r], scale, nm));
      // pack to f16x2 dwords: pd[nt][h] = (p[2h], p[2h+1]) for keys nt*16+quad*4+{2h,2h+1}
      uint32_t pd[4][2];
      #pragma unroll
      for (int nt = 0; nt < 4; ++nt) {
        f16x2 lo2, hi2;
        lo2[0] = (_Float16)sacc[mt][nt][0]; lo2[1] = (_Float16)sacc[mt][nt][1];
        hi2[0] = (_Float16)sacc[mt][nt][2]; hi2[1] = (_Float16)sacc[mt][nt][3];
        pd[nt][0] = __builtin_bit_cast(uint32_t, lo2);
        pd[nt][1] = __builtin_bit_cast(uint32_t, hi2);
      }
      // rebuild A-fragments: pf[mt][k2][j] = P[q=l15][key = k2*32 + quad*8 + j]
      #pragma unroll
      for (int k2 = 0; k2 < 2; ++k2) {
        uint32_t w[4];
        #pragma unroll
        for (int h = 0; h < 2; ++h) {
          uint32_t a0v = (uint32_t)__shfl((int)pd[2 * k2][h],     idxA);
          uint32_t a1v = (uint32_t)__shfl((int)pd[2 * k2 + 1][h], idxA);
          w[h] = hiNt ? a1v : a0v;
          uint32_t b0v = (uint32_t)__shfl((int)pd[2 * k2][h],     idxB);
          uint32_t b1v = (uint32_t)__shfl((int)pd[2 * k2 + 1][h], idxB);
          w[2 + h] = hiNt ? b1v : b0v;
        }
        u32x4 wv = {w[0], w[1], w[2], w[3]};
        pf[mt][k2] = __builtin_bit_cast(f16x8, wv);
      }
    }

    // ---- O += P V ; li += P*1 ----
    #pragma unroll
    for (int k2 = 0; k2 < 2; ++k2) {
      f16x8 vf[8];
      #pragma unroll
      for (int nt = 0; nt < 8; ++nt) {
        int rv = nt * 16 + l15;
        int pv = (k2 * 4 + quad) ^ (rv & 7);
        vf[nt] = *(const f16x8*)((const char*)Vs + rv * 128 + pv * 16);
      }
      __builtin_amdgcn_s_setprio(1);
      #pragma unroll
      for (int mt = 0; mt < 2; ++mt)
        liacc[mt] = __builtin_amdgcn_mfma_f32_16x16x32_f16(pf[mt][k2], ones, liacc[mt], 0, 0, 0);
      #pragma unroll
      for (int mt = 0; mt < 2; ++mt)
        #pragma unroll
        for (int nt = 0; nt < 8; ++nt)
          oacc[mt][nt] = __builtin_amdgcn_mfma_f32_16x16x32_f16(pf[mt][k2], vf[nt], oacc[mt][nt], 0, 0, 0);
      __builtin_amdgcn_s_setprio(0);
    }

    // barrier B: all waves done reading V[kt]; drains K[kt+1] stage
    __syncthreads();
    if (kt + 1 < nkt) stageV(kt + 1);   // covered by next QK, drained at barrier A
  }

  // epilogue: O / l  (oacc/liacc row q = quad*4+r, col d = nt*16+l15)
  #pragma unroll
  for (int mt = 0; mt < 2; ++mt)
    #pragma unroll
    for (int r = 0; r < 4; ++r) {
      float inv = 1.0f / liacc[mt][r];
      size_t row = (size_t)b * S + qt * 128 + wave * 32 + mt * 16 + quad * 4 + r;
      #pragma unroll
      for (int nt = 0; nt < 8; ++nt)
        O[row * 4096 + hq * 128 + nt * 16 + l15] = (_Float16)(oacc[mt][nt][r] * inv);
    }
}

extern "C" void kernel_launch(void* const* d_in, const int* in_sizes, int n_in,
                              void* d_out, int out_size, void* d_ws, size_t ws_size,
                              hipStream_t stream) {
  const float* x  = (const float*)d_in[0];
  const float* wq = (const float*)d_in[1];
  const float* wk = (const float*)d_in[2];
  const float* wv = (const float*)d_in[3];
  const float* wo = (const float*)d_in[4];
  const int*   sp = (const int*)d_in[5];

  const int dim = 4096, kvdim = 1024;
  const int T = in_sizes[0] / dim;   // 4096 tokens (b*s)
  const int B = 2;
  const int S = T / B;               // 2048

  // workspace layout (fp16), total ~160 MiB
  _Float16* xb   = (_Float16*)d_ws;
  _Float16* wqb  = xb   + (size_t)T * dim;        // wq (4096 rows)
  _Float16* wkvb = wqb  + (size_t)dim * dim;      // wk (1024) then wv (1024), contiguous after wq
  _Float16* wob  = wkvb + (size_t)2 * kvdim * dim;
  _Float16* XQ   = wob  + (size_t)dim * dim;
  _Float16* XK   = XQ   + (size_t)T * dim;
  _Float16* VT   = XK   + (size_t)T * kvdim;
  _Float16* AO   = xb;               // alias: xb dead after projections

  // one launch: all five fp32->fp16 conversions
  cvt5_kernel<<<dim3(2048, 5), 256, 0, stream>>>(
      x, wq, wk, wv, wo,
      xb, wqb, wkvb, wkvb + (size_t)kvdim * dim, wob,
      (int)((size_t)T * dim / 4), (int)((size_t)dim * dim / 4),
      (int)((size_t)kvdim * dim / 4), (int)((size_t)kvdim * dim / 4),
      (int)((size_t)dim * dim / 4));

  // one launch: Q+K+V projections (wq|wk|wv contiguous as B rows [0,6144))
  gemm_qkv<<<dim3((dim + 2 * kvdim) / 128, T / 128), 256, 0, stream>>>(
      xb, wqb, XQ, XK, VT, T, dim + 2 * kvdim, dim);

  // one launch: RoPE on XQ and XK (in place)
  rope2_kernel<<<dim3(4096, 2), 256, 0, stream>>>(
      XQ, XK, sp, S - 1, (int)((size_t)T * dim / 2), (int)((size_t)T * kvdim / 2));

  // attention
  flash_kernel<<<dim3(S / 128, 32, B), 256, 0, stream>>>(XQ, XK, VT, AO, S, T);

  // output projection (fp32 out): 128x256 tile, 512 blocks = one full generation
  gemm_wide<<<dim3(dim / 256, T / 128), 256, 0, stream>>>(
      AO, wob, (float*)d_out, T, dim, dim);
}